// Round 8
// baseline (1024.313 us; speedup 1.0000x reference)
//
#include <hip/hip_runtime.h>
#include <math.h>

#define FRAME 128
#define HOPW 64
#define SLEN 65536
#define IRLEN 1024
#define NFB 1006          // feedback iterations
#define RMASK 2047
#define PI_D 3.14159265358979323846

__device__ __forceinline__ float clip1(float v) { return fminf(1.0f, fmaxf(-1.0f, v)); }

// Raw barrier: drains LDS ops only; global loads/stores stay in flight.
__device__ __forceinline__ void loop_barrier() {
    __builtin_amdgcn_sched_barrier(0);
    asm volatile("s_waitcnt lgkmcnt(0)" ::: "memory");
    __builtin_amdgcn_s_barrier();
    __builtin_amdgcn_sched_barrier(0);
}

// Single-barrier pipeline. 768 threads = 12 waves. kg = tid/192 (wave-uniform
// 32-tap group), ob = tid%192 -> 6 conv outputs/thread (37-float IR window in
// VGPRs). Phase P_i: tail-apply conv_i (waves 2-5) || OLA block i (wave 0) ||
// x-commit (wave 11) || per-wave self-compute of w_{i+1} slice || FMA partials
// of conv_{i+1}. Head v-values live in vbuf (ring never stores them); w for
// OLA in wb. part/vbuf/wb double-buffered with compile-time parity (unroll 2).
__global__ __launch_bounds__(768) void howl_fused(const float* __restrict__ x,
                                                  const float* __restrict__ ir,
                                                  float* __restrict__ out) {
    __shared__ __align__(16) float ring[2048];      // raw x + tail-applies ONLY
    __shared__ __align__(16) float part[2][4][1152];
    __shared__ float irl[IRLEN];
    __shared__ float vbuf[2][128];   // head v values (only [64,128) consumed)
    __shared__ float wb[2][128];     // w_i for OLA
    __shared__ float red1[1024];
    __shared__ float red2[1024];
    __shared__ float invfs;

    const int tid = threadIdx.x;
    const int lane = tid & 63;
    const int wvid = tid >> 6;
    const int kg = tid / 192;
    const int ob = tid % 192;
    const int q = ob * 6;
    const int lo = q - kg * 32 - 31;
    const int s = kg * 32 + (lane & 31);       // this thread's w-slice index
    const bool wlow = (ob < 64) && (lane < 32);  // one writer lane per w-slot

    // ---- prologue: stage IR + raw x window ----
    for (int idx = tid; idx < IRLEN; idx += 768) irl[idx] = ir[idx];
    for (int idx = tid; idx < 1216; idx += 768) ring[idx] = x[idx];  // raw
    if (tid >= 513) { red1[tid] = -INFINITY; red2[tid] = 0.f; }
    if (tid < 256) { red1[768 + tid] = -INFINITY; red2[768 + tid] = 0.f; }
    __syncthreads();

    // ---- DFT power spectrum (4-way ILP recurrence, double precision) ----
    if (tid < 513) {
        double th = -2.0 * PI_D * (double)tid / 1024.0;
        double c4 = cos(4.0 * th), s4 = sin(4.0 * th);
        double wr0 = 1.0,           wi0 = 0.0;
        double wr1 = cos(th),       wi1 = sin(th);
        double wr2 = cos(2.0 * th), wi2 = sin(2.0 * th);
        double wr3 = cos(3.0 * th), wi3 = sin(3.0 * th);
        double ar0 = 0, ai0 = 0, ar1 = 0, ai1 = 0, ar2 = 0, ai2 = 0, ar3 = 0, ai3 = 0;
        for (int m = 0; m < 256; ++m) {
            double x0 = irl[4 * m], x1 = irl[4 * m + 1], x2 = irl[4 * m + 2], x3 = irl[4 * m + 3];
            ar0 += x0 * wr0; ai0 += x0 * wi0;
            ar1 += x1 * wr1; ai1 += x1 * wi1;
            ar2 += x2 * wr2; ai2 += x2 * wi2;
            ar3 += x3 * wr3; ai3 += x3 * wi3;
            double t;
            t = wr0 * c4 - wi0 * s4; wi0 = wr0 * s4 + wi0 * c4; wr0 = t;
            t = wr1 * c4 - wi1 * s4; wi1 = wr1 * s4 + wi1 * c4; wr1 = t;
            t = wr2 * c4 - wi2 * s4; wi2 = wr2 * s4 + wi2 * c4; wr2 = t;
            t = wr3 * c4 - wi3 * s4; wi3 = wr3 * s4 + wi3 * c4; wr3 = t;
        }
        double re = (ar0 + ar1) + (ar2 + ar3);
        double im = (ai0 + ai1) + (ai2 + ai3);
        float mag = (float)sqrt(re * re + im * im);
        float pw = mag * mag;
        double ph = atan2(im, re);
        int ok = (ph > -0.1 && ph < 0.1) ? 1 : 0;
        red1[tid] = ok ? pw : -INFINITY;
        red2[tid] = pw;
    }
    __syncthreads();
    for (int st = 512; st > 0; st >>= 1) {
        if (tid < st) {
            red1[tid] = fmaxf(red1[tid], red1[tid + st]);
            red2[tid] = red2[tid] + red2[tid + st];
        }
        __syncthreads();
    }
    if (tid == 0) {
        float peak = red1[0];
        float MLG = red2[0] / 513.0f;
        float MSG = -10.0f * log10f(peak / MLG);
        float target_gain = MSG + 2.0f;
        float mean_gain = 10.0f * log10f(MLG);
        invfs = powf(0.5f, (target_gain - mean_gain) / 6.0f);
    }
    __syncthreads();
    const float fbc = invfs;

    float wir[37];
#pragma unroll
    for (int j = 0; j < 37; ++j) {
        int idx = lo + j;
        wir[j] = (idx >= 0 && idx < IRLEN) ? irl[idx] / fbc : 0.f;
    }

    const float hann_s = (float)(0.5 * (1.0 - cos(PI_D * (double)s / 64.0)));

    // ---- pipeline priming ----
    float wreg = hann_s * ring[s];          // w_0 (raw x)
    if (wlow) wb[0][s] = wreg;              // w_0 for OLA
    if (tid < 64) vbuf[1][64 + tid] = ring[64 + tid];  // "head v" for i=0 = raw x
    float tl = 0.f, xv = 0.f;
    if (wvid == 11) xv = x[1216 + lane];    // prefetch for P_0 commit
    __syncthreads();

    // prologue FMA: conv_0 partials -> part[0]
    {
        float a0 = 0, a1 = 0, a2 = 0, a3 = 0, a4 = 0, a5 = 0;
#pragma unroll
        for (int kk = 0; kk < 32; ++kk) {
            float sc = __int_as_float(__builtin_amdgcn_readlane(__float_as_int(wreg), 31 - kk));
            a0 = fmaf(sc, wir[kk + 0], a0);
            a1 = fmaf(sc, wir[kk + 1], a1);
            a2 = fmaf(sc, wir[kk + 2], a2);
            a3 = fmaf(sc, wir[kk + 3], a3);
            a4 = fmaf(sc, wir[kk + 4], a4);
            a5 = fmaf(sc, wir[kk + 5], a5);
        }
        float* pw = &part[0][kg][q];
        *(float2*)(pw + 0) = make_float2(a0, a1);
        *(float2*)(pw + 2) = make_float2(a2, a3);
        *(float2*)(pw + 4) = make_float2(a4, a5);
    }
    loop_barrier();

    auto body = [&](int i, const float* cur, float* nxt,
                    const float* vb_r, float* vb_w,
                    const float* wb_r, float* wb_w) {
        const int base = i * HOPW;

        // OLA block i (wave 0) / x-commit + prefetch (wave 11)
        if (wvid == 0) {
            float w0v = wb_r[lane];
            float w1v = wb_r[64 + lane];
            out[base + lane] = clip1(w0v + tl);
            tl = w1v;
        } else if (wvid == 11) {
            int pos = base + 1216 + lane;
            if (pos < SLEN) ring[pos & RMASK] = clip1(xv);
            int np = pos + HOPW;
            xv = (np < SLEN) ? x[np] : 0.f;
        }

        // tail-apply conv_i: p in [128,1152) -> slots [base+192, base+1216)
        if (tid >= 128 && tid < 384) {
            int p = 128 + 4 * (tid - 128);
            float4 g0 = *(const float4*)&cur[p];
            float4 g1 = *(const float4*)&cur[1152 + p];
            float4 g2 = *(const float4*)&cur[2304 + p];
            float4 g3 = *(const float4*)&cur[3456 + p];
            int slot = (base + 64 + p) & RMASK;
            float4 rv = *(float4*)&ring[slot];
            rv.x = clip1(rv.x + (((g0.x + g1.x) + g2.x) + g3.x));
            rv.y = clip1(rv.y + (((g0.y + g1.y) + g2.y) + g3.y));
            rv.z = clip1(rv.z + (((g0.z + g1.z) + g2.z) + g3.z));
            rv.w = clip1(rv.w + (((g0.w + g1.w) + g2.w) + g3.w));
            *(float4*)&ring[slot] = rv;
        }

        // self-compute w_{i+1} slice (all waves): head of conv_i at p = s
        {
            float c0 = cur[s], c1 = cur[1152 + s], c2 = cur[2304 + s], c3 = cur[3456 + s];
            float rr = (kg < 2) ? vb_r[64 + s] : ring[(base + 64 + s) & RMASK];
            float v = clip1(rr + (((c0 + c1) + c2) + c3));
            float wn = hann_s * v;
            if (kg >= 2 && wlow) vb_w[s] = v;   // head v for next phase's kg<2
            if (wlow) wb_w[s] = wn;             // w_{i+1} for OLA
            wreg = wn;
        }

        // FMA partials of conv_{i+1} -> nxt
        float a0 = 0, a1 = 0, a2 = 0, a3 = 0, a4 = 0, a5 = 0;
#pragma unroll
        for (int kk = 0; kk < 32; ++kk) {
            float sc = __int_as_float(__builtin_amdgcn_readlane(__float_as_int(wreg), 31 - kk));
            a0 = fmaf(sc, wir[kk + 0], a0);
            a1 = fmaf(sc, wir[kk + 1], a1);
            a2 = fmaf(sc, wir[kk + 2], a2);
            a3 = fmaf(sc, wir[kk + 3], a3);
            a4 = fmaf(sc, wir[kk + 4], a4);
            a5 = fmaf(sc, wir[kk + 5], a5);
        }
        float* pw = nxt + kg * 1152 + q;
        *(float2*)(pw + 0) = make_float2(a0, a1);
        *(float2*)(pw + 2) = make_float2(a2, a3);
        *(float2*)(pw + 4) = make_float2(a4, a5);

        loop_barrier();
    };

    const float* P0 = &part[0][0][0];
    float* P1 = &part[1][0][0];
#pragma unroll 1
    for (int i = 0; i < NFB; i += 2) {   // NFB even -> parities compile-time
        body(i,     P0, (float*)P1, vbuf[1], vbuf[0], wb[0], wb[1]);
        body(i + 1, P1, (float*)P0, vbuf[0], vbuf[1], wb[1], wb[0]);
    }

    // ---- epilogue: blocks 1006/1007 + zero tail ----
    // w_1006 is in wb[(NFB)&1] = wb[0]; tl = w_1005[64+lane] (wave 0).
    if (wvid == 0) {
        out[64384 + lane] = clip1(wb[0][lane] + tl);
        out[64448 + lane] = clip1(wb[0][64 + lane]);
    }
    for (int idx = 64512 + tid; idx < SLEN; idx += 768) out[idx] = 0.f;
}

extern "C" void kernel_launch(void* const* d_in, const int* in_sizes, int n_in,
                              void* d_out, int out_size, void* d_ws, size_t ws_size,
                              hipStream_t stream) {
    const float* x = (const float*)d_in[0];
    const float* ir = (const float*)d_in[1];
    float* out = (float*)d_out;
    (void)d_ws; (void)ws_size; (void)in_sizes; (void)n_in; (void)out_size;

    hipLaunchKernelGGL(howl_fused, dim3(1), dim3(768), 0, stream, x, ir, out);
}

// Round 9
// 1020.552 us; speedup vs baseline: 1.0037x; 1.0037x over previous
//
#include <hip/hip_runtime.h>
#include <math.h>

#define FRAME 128
#define HOPW 64
#define SLEN 65536
#define IRLEN 1024
#define NFB 1006          // feedback iterations
#define RMASK 2047
#define PI_D 3.14159265358979323846

// clip to [-1,1]: single v_med3_f32 (bitwise == fminf(fmaxf(v,-1),1) for finite v)
__device__ __forceinline__ float clip1(float v) { return __builtin_amdgcn_fmed3f(v, -1.0f, 1.0f); }

// Raw barrier: drains LDS ops only; global loads/stores stay in flight.
__device__ __forceinline__ void loop_barrier() {
    __builtin_amdgcn_sched_barrier(0);
    asm volatile("s_waitcnt lgkmcnt(0)" ::: "memory");
    __builtin_amdgcn_s_barrier();
    __builtin_amdgcn_sched_barrier(0);
}

// Single-barrier pipeline (round-8 structure) + split tail-apply:
// tail LDS reads issue at phase TOP (hidden under FMA), RMW+write at phase END.
// 768 threads = 12 waves. kg = tid/192 (wave-uniform 32-tap group), ob = tid%192
// -> 6 conv outputs/thread (37-float IR window in VGPRs). Head v-values in vbuf;
// w for OLA in wb; part/vbuf/wb double-buffered with compile-time parity.
__global__ __launch_bounds__(768) void howl_fused(const float* __restrict__ x,
                                                  const float* __restrict__ ir,
                                                  float* __restrict__ out) {
    __shared__ __align__(16) float ring[2048];      // raw x + tail-applies ONLY
    __shared__ __align__(16) float part[2][4][1152];
    __shared__ float irl[IRLEN];
    __shared__ float vbuf[2][128];   // head v values (only [64,128) consumed)
    __shared__ float wb[2][128];     // w_i for OLA
    __shared__ float red1[1024];
    __shared__ float red2[1024];
    __shared__ float invfs;

    const int tid = threadIdx.x;
    const int lane = tid & 63;
    const int wvid = tid >> 6;
    const int kg = tid / 192;
    const int ob = tid % 192;
    const int q = ob * 6;
    const int lo = q - kg * 32 - 31;
    const int s = kg * 32 + (lane & 31);       // this thread's w-slice index
    const bool wlow = (ob < 64) && (lane < 32);  // one writer lane per w-slot
    const bool tailw = (tid >= 128 && tid < 384);

    // ---- prologue: stage IR + raw x window ----
    for (int idx = tid; idx < IRLEN; idx += 768) irl[idx] = ir[idx];
    for (int idx = tid; idx < 1216; idx += 768) ring[idx] = x[idx];  // raw
    if (tid >= 513) { red1[tid] = -INFINITY; red2[tid] = 0.f; }
    if (tid < 256) { red1[768 + tid] = -INFINITY; red2[768 + tid] = 0.f; }
    __syncthreads();

    // ---- DFT power spectrum (4-way ILP recurrence, double precision) ----
    if (tid < 513) {
        double th = -2.0 * PI_D * (double)tid / 1024.0;
        double c4 = cos(4.0 * th), s4 = sin(4.0 * th);
        double wr0 = 1.0,           wi0 = 0.0;
        double wr1 = cos(th),       wi1 = sin(th);
        double wr2 = cos(2.0 * th), wi2 = sin(2.0 * th);
        double wr3 = cos(3.0 * th), wi3 = sin(3.0 * th);
        double ar0 = 0, ai0 = 0, ar1 = 0, ai1 = 0, ar2 = 0, ai2 = 0, ar3 = 0, ai3 = 0;
        for (int m = 0; m < 256; ++m) {
            double x0 = irl[4 * m], x1 = irl[4 * m + 1], x2 = irl[4 * m + 2], x3 = irl[4 * m + 3];
            ar0 += x0 * wr0; ai0 += x0 * wi0;
            ar1 += x1 * wr1; ai1 += x1 * wi1;
            ar2 += x2 * wr2; ai2 += x2 * wi2;
            ar3 += x3 * wr3; ai3 += x3 * wi3;
            double t;
            t = wr0 * c4 - wi0 * s4; wi0 = wr0 * s4 + wi0 * c4; wr0 = t;
            t = wr1 * c4 - wi1 * s4; wi1 = wr1 * s4 + wi1 * c4; wr1 = t;
            t = wr2 * c4 - wi2 * s4; wi2 = wr2 * s4 + wi2 * c4; wr2 = t;
            t = wr3 * c4 - wi3 * s4; wi3 = wr3 * s4 + wi3 * c4; wr3 = t;
        }
        double re = (ar0 + ar1) + (ar2 + ar3);
        double im = (ai0 + ai1) + (ai2 + ai3);
        float mag = (float)sqrt(re * re + im * im);
        float pw = mag * mag;
        double ph = atan2(im, re);
        int ok = (ph > -0.1 && ph < 0.1) ? 1 : 0;
        red1[tid] = ok ? pw : -INFINITY;
        red2[tid] = pw;
    }
    __syncthreads();
    for (int st = 512; st > 0; st >>= 1) {
        if (tid < st) {
            red1[tid] = fmaxf(red1[tid], red1[tid + st]);
            red2[tid] = red2[tid] + red2[tid + st];
        }
        __syncthreads();
    }
    if (tid == 0) {
        float peak = red1[0];
        float MLG = red2[0] / 513.0f;
        float MSG = -10.0f * log10f(peak / MLG);
        float target_gain = MSG + 2.0f;
        float mean_gain = 10.0f * log10f(MLG);
        invfs = powf(0.5f, (target_gain - mean_gain) / 6.0f);
    }
    __syncthreads();
    const float fbc = invfs;

    float wir[37];
#pragma unroll
    for (int j = 0; j < 37; ++j) {
        int idx = lo + j;
        wir[j] = (idx >= 0 && idx < IRLEN) ? irl[idx] / fbc : 0.f;
    }

    const float hann_s = (float)(0.5 * (1.0 - cos(PI_D * (double)s / 64.0)));

    // ---- pipeline priming ----
    float wreg = hann_s * ring[s];          // w_0 (raw x)
    if (wlow) wb[0][s] = wreg;              // w_0 for OLA
    if (tid < 64) vbuf[1][64 + tid] = ring[64 + tid];  // "head v" for i=0 = raw x
    float tl = 0.f, xv = 0.f;
    if (wvid == 11) xv = x[1216 + lane];    // prefetch for P_0 commit
    __syncthreads();

    // prologue FMA: conv_0 partials -> part[0]
    {
        float a0 = 0, a1 = 0, a2 = 0, a3 = 0, a4 = 0, a5 = 0;
#pragma unroll
        for (int kk = 0; kk < 32; ++kk) {
            float sc = __int_as_float(__builtin_amdgcn_readlane(__float_as_int(wreg), 31 - kk));
            a0 = fmaf(sc, wir[kk + 0], a0);
            a1 = fmaf(sc, wir[kk + 1], a1);
            a2 = fmaf(sc, wir[kk + 2], a2);
            a3 = fmaf(sc, wir[kk + 3], a3);
            a4 = fmaf(sc, wir[kk + 4], a4);
            a5 = fmaf(sc, wir[kk + 5], a5);
        }
        float* pw = &part[0][kg][q];
        *(float2*)(pw + 0) = make_float2(a0, a1);
        *(float2*)(pw + 2) = make_float2(a2, a3);
        *(float2*)(pw + 4) = make_float2(a4, a5);
    }
    loop_barrier();

    auto body = [&](int i, const float* cur, float* nxt,
                    const float* vb_r, float* vb_w,
                    const float* wb_r, float* wb_w) {
        const int base = i * HOPW;

        // (1) EARLY: tail-apply LDS reads (conv_i, p in [128,1152)) — consumed
        // after the FMA phase; slots [base+192, base+1216) have no other writer
        // this phase, so read-early/write-late is hazard-free.
        float4 g0, g1, g2, g3, rvv;
        int slotT = 0;
        if (tailw) {
            int p = 128 + 4 * (tid - 128);
            g0 = *(const float4*)&cur[p];
            g1 = *(const float4*)&cur[1152 + p];
            g2 = *(const float4*)&cur[2304 + p];
            g3 = *(const float4*)&cur[3456 + p];
            slotT = (base + 64 + p) & RMASK;
            rvv = *(float4*)&ring[slotT];
        }
        __builtin_amdgcn_sched_barrier(0);   // pin the reads at phase top

        // (2) OLA block i (wave 0) / x-commit + prefetch (wave 11)
        if (wvid == 0) {
            float w0v = wb_r[lane];
            float w1v = wb_r[64 + lane];
            out[base + lane] = clip1(w0v + tl);
            tl = w1v;
        } else if (wvid == 11) {
            int pos = base + 1216 + lane;
            if (pos < SLEN) ring[pos & RMASK] = clip1(xv);
            int np = pos + HOPW;
            xv = (np < SLEN) ? x[np] : 0.f;
        }

        // (3) self-compute w_{i+1} slice (all waves): head of conv_i at p = s
        {
            float c0 = cur[s], c1 = cur[1152 + s], c2 = cur[2304 + s], c3 = cur[3456 + s];
            float rr = (kg < 2) ? vb_r[64 + s] : ring[(base + 64 + s) & RMASK];
            float v = clip1(rr + (((c0 + c1) + c2) + c3));
            float wn = hann_s * v;
            if (kg >= 2 && wlow) vb_w[s] = v;   // head v for next phase's kg<2
            if (wlow) wb_w[s] = wn;             // w_{i+1} for OLA
            wreg = wn;
        }

        // (4) FMA partials of conv_{i+1} -> nxt
        float a0 = 0, a1 = 0, a2 = 0, a3 = 0, a4 = 0, a5 = 0;
#pragma unroll
        for (int kk = 0; kk < 32; ++kk) {
            float sc = __int_as_float(__builtin_amdgcn_readlane(__float_as_int(wreg), 31 - kk));
            a0 = fmaf(sc, wir[kk + 0], a0);
            a1 = fmaf(sc, wir[kk + 1], a1);
            a2 = fmaf(sc, wir[kk + 2], a2);
            a3 = fmaf(sc, wir[kk + 3], a3);
            a4 = fmaf(sc, wir[kk + 4], a4);
            a5 = fmaf(sc, wir[kk + 5], a5);
        }
        float* pw = nxt + kg * 1152 + q;
        *(float2*)(pw + 0) = make_float2(a0, a1);
        *(float2*)(pw + 2) = make_float2(a2, a3);
        *(float2*)(pw + 4) = make_float2(a4, a5);

        // (5) LATE: tail-apply RMW + write (reads from step 1 long since landed)
        if (tailw) {
            rvv.x = clip1(rvv.x + (((g0.x + g1.x) + g2.x) + g3.x));
            rvv.y = clip1(rvv.y + (((g0.y + g1.y) + g2.y) + g3.y));
            rvv.z = clip1(rvv.z + (((g0.z + g1.z) + g2.z) + g3.z));
            rvv.w = clip1(rvv.w + (((g0.w + g1.w) + g2.w) + g3.w));
            *(float4*)&ring[slotT] = rvv;
        }

        loop_barrier();
    };

    const float* P0 = &part[0][0][0];
    float* P1 = &part[1][0][0];
#pragma unroll 1
    for (int i = 0; i < NFB; i += 2) {   // NFB even -> parities compile-time
        body(i,     P0, (float*)P1, vbuf[1], vbuf[0], wb[0], wb[1]);
        body(i + 1, P1, (float*)P0, vbuf[0], vbuf[1], wb[1], wb[0]);
    }

    // ---- epilogue: blocks 1006/1007 + zero tail ----
    if (wvid == 0) {
        out[64384 + lane] = clip1(wb[0][lane] + tl);
        out[64448 + lane] = clip1(wb[0][64 + lane]);
    }
    for (int idx = 64512 + tid; idx < SLEN; idx += 768) out[idx] = 0.f;
}

extern "C" void kernel_launch(void* const* d_in, const int* in_sizes, int n_in,
                              void* d_out, int out_size, void* d_ws, size_t ws_size,
                              hipStream_t stream) {
    const float* x = (const float*)d_in[0];
    const float* ir = (const float*)d_in[1];
    float* out = (float*)d_out;
    (void)d_ws; (void)ws_size; (void)in_sizes; (void)n_in; (void)out_size;

    hipLaunchKernelGGL(howl_fused, dim3(1), dim3(768), 0, stream, x, ir, out);
}

// Round 10
// 1003.849 us; speedup vs baseline: 1.0204x; 1.0166x over previous
//
#include <hip/hip_runtime.h>
#include <math.h>

#define FRAME 128
#define HOPW 64
#define SLEN 65536
#define IRLEN 1024
#define NFB 1006          // feedback iterations
#define RMASK 2047
#define PI_D 3.14159265358979323846

// clip to [-1,1]: single v_med3_f32 (bitwise == fminf(fmaxf(v,-1),1) for finite v)
__device__ __forceinline__ float clip1(float v) { return __builtin_amdgcn_fmed3f(v, -1.0f, 1.0f); }

// Raw barrier: drains LDS ops only; global loads/stores stay in flight.
__device__ __forceinline__ void loop_barrier() {
    __builtin_amdgcn_sched_barrier(0);
    asm volatile("s_waitcnt lgkmcnt(0)" ::: "memory");
    __builtin_amdgcn_s_barrier();
    __builtin_amdgcn_sched_barrier(0);
}

// Single-barrier pipeline (round-8/9 structure), head-critical reads first.
// 768 threads = 12 waves. kg = tid/192 (wave-uniform 32-tap group), ob = tid%192
// -> 6 conv outputs/thread (37-float IR window in VGPRs). Head v-values in vbuf;
// w for OLA in wb; part/vbuf/wb double-buffered with compile-time parity.
__global__ __launch_bounds__(768) void howl_fused(const float* __restrict__ x,
                                                  const float* __restrict__ ir,
                                                  float* __restrict__ out) {
    __shared__ __align__(16) float ring[2048];      // raw x + tail-applies ONLY
    __shared__ __align__(16) float part[2][4][1152];
    __shared__ float irl[IRLEN];
    __shared__ float vbuf[2][128];   // head v values (only [64,128) consumed)
    __shared__ float wb[2][128];     // w_i for OLA
    __shared__ float red1[1024];
    __shared__ float red2[1024];
    __shared__ float invfs;

    const int tid = threadIdx.x;
    const int lane = tid & 63;
    const int wvid = tid >> 6;
    const int kg = tid / 192;
    const int ob = tid % 192;
    const int q = ob * 6;
    const int lo = q - kg * 32 - 31;
    const int s = kg * 32 + (lane & 31);       // this thread's w-slice index
    const bool wlow = (ob < 64) && (lane < 32);  // one writer lane per w-slot
    const bool tailw = (tid >= 128 && tid < 384);

    // ---- prologue: stage IR + raw x window + radix-2 folded DFT inputs ----
    for (int idx = tid; idx < IRLEN; idx += 768) irl[idx] = ir[idx];
    for (int idx = tid; idx < 1216; idx += 768) ring[idx] = x[idx];  // raw
    // f64 radix-2 fold staged in part scratch (overwritten later, barrier-safe)
    double* ydp = (double*)&part[0][0][0];   // 512 doubles: ir[n]+ir[n+512]
    double* ydm = ydp + 512;                 // 512 doubles: ir[n]-ir[n+512]
    if (tid < 512) {
        double a = (double)ir[tid], b = (double)ir[tid + 512];
        ydp[tid] = a + b;
        ydm[tid] = a - b;
    }
    if (tid >= 513) { red1[tid] = -INFINITY; red2[tid] = 0.f; }
    if (tid < 256) { red1[768 + tid] = -INFINITY; red2[768 + tid] = 0.f; }
    __syncthreads();

    // ---- DFT power spectrum: folded length-512 sum, 4-way ILP, f64 ----
    if (tid < 513) {
        double th = -2.0 * PI_D * (double)tid / 1024.0;
        double c4 = cos(4.0 * th), s4 = sin(4.0 * th);
        double wr0 = 1.0,           wi0 = 0.0;
        double wr1 = cos(th),       wi1 = sin(th);
        double wr2 = cos(2.0 * th), wi2 = sin(2.0 * th);
        double wr3 = cos(3.0 * th), wi3 = sin(3.0 * th);
        double ar0 = 0, ai0 = 0, ar1 = 0, ai1 = 0, ar2 = 0, ai2 = 0, ar3 = 0, ai3 = 0;
        const double* ys = (tid & 1) ? ydm : ydp;
        for (int m = 0; m < 128; ++m) {
            double x0 = ys[4 * m], x1 = ys[4 * m + 1], x2 = ys[4 * m + 2], x3 = ys[4 * m + 3];
            ar0 += x0 * wr0; ai0 += x0 * wi0;
            ar1 += x1 * wr1; ai1 += x1 * wi1;
            ar2 += x2 * wr2; ai2 += x2 * wi2;
            ar3 += x3 * wr3; ai3 += x3 * wi3;
            double t;
            t = wr0 * c4 - wi0 * s4; wi0 = wr0 * s4 + wi0 * c4; wr0 = t;
            t = wr1 * c4 - wi1 * s4; wi1 = wr1 * s4 + wi1 * c4; wr1 = t;
            t = wr2 * c4 - wi2 * s4; wi2 = wr2 * s4 + wi2 * c4; wr2 = t;
            t = wr3 * c4 - wi3 * s4; wi3 = wr3 * s4 + wi3 * c4; wr3 = t;
        }
        double re = (ar0 + ar1) + (ar2 + ar3);
        double im = (ai0 + ai1) + (ai2 + ai3);
        float mag = (float)sqrt(re * re + im * im);
        float pw = mag * mag;
        double ph = atan2(im, re);
        int ok = (ph > -0.1 && ph < 0.1) ? 1 : 0;
        red1[tid] = ok ? pw : -INFINITY;
        red2[tid] = pw;
    }
    __syncthreads();
    for (int st = 512; st > 0; st >>= 1) {
        if (tid < st) {
            red1[tid] = fmaxf(red1[tid], red1[tid + st]);
            red2[tid] = red2[tid] + red2[tid + st];
        }
        __syncthreads();
    }
    if (tid == 0) {
        float peak = red1[0];
        float MLG = red2[0] / 513.0f;
        float MSG = -10.0f * log10f(peak / MLG);
        float target_gain = MSG + 2.0f;
        float mean_gain = 10.0f * log10f(MLG);
        invfs = powf(0.5f, (target_gain - mean_gain) / 6.0f);
    }
    __syncthreads();
    const float fbc = invfs;

    float wir[37];
#pragma unroll
    for (int j = 0; j < 37; ++j) {
        int idx = lo + j;
        wir[j] = (idx >= 0 && idx < IRLEN) ? irl[idx] / fbc : 0.f;
    }

    const float hann_s = (float)(0.5 * (1.0 - cos(PI_D * (double)s / 64.0)));

    // ---- pipeline priming ----
    float wreg = hann_s * ring[s];          // w_0 (raw x)
    if (wlow) wb[0][s] = wreg;              // w_0 for OLA
    if (tid < 64) vbuf[1][64 + tid] = ring[64 + tid];  // "head v" for i=0 = raw x
    float tl = 0.f, xv = 0.f;
    if (wvid == 11) xv = x[1216 + lane];    // prefetch for P_0 commit
    __syncthreads();

    // prologue FMA: conv_0 partials -> part[0]
    {
        float a0 = 0, a1 = 0, a2 = 0, a3 = 0, a4 = 0, a5 = 0;
#pragma unroll
        for (int kk = 0; kk < 32; ++kk) {
            float sc = __int_as_float(__builtin_amdgcn_readlane(__float_as_int(wreg), 31 - kk));
            a0 = fmaf(sc, wir[kk + 0], a0);
            a1 = fmaf(sc, wir[kk + 1], a1);
            a2 = fmaf(sc, wir[kk + 2], a2);
            a3 = fmaf(sc, wir[kk + 3], a3);
            a4 = fmaf(sc, wir[kk + 4], a4);
            a5 = fmaf(sc, wir[kk + 5], a5);
        }
        float* pw = &part[0][kg][q];
        *(float2*)(pw + 0) = make_float2(a0, a1);
        *(float2*)(pw + 2) = make_float2(a2, a3);
        *(float2*)(pw + 4) = make_float2(a4, a5);
    }
    loop_barrier();

    auto body = [&](int i, const float* cur, float* nxt,
                    const float* vb_r, float* vb_w,
                    const float* wb_r, float* wb_w) {
        const int base = i * HOPW;

        // (0) HEAD-CRITICAL reads first: 4 part values + ONE selected rr read.
        float c0 = cur[s], c1 = cur[1152 + s], c2 = cur[2304 + s], c3 = cur[3456 + s];
        const float* rptr = (kg < 2) ? &vb_r[64 + s]
                                     : &ring[(base + 64 + s) & RMASK];
        float rr = *rptr;

        // (1) tail-apply early reads (conv_i, p in [128,1152)) — consumed after
        // the FMA phase; slots [base+192, base+1216) have no other writer.
        float4 g0, g1, g2, g3, rvv;
        int slotT = 0;
        if (tailw) {
            int p = 128 + 4 * (tid - 128);
            g0 = *(const float4*)&cur[p];
            g1 = *(const float4*)&cur[1152 + p];
            g2 = *(const float4*)&cur[2304 + p];
            g3 = *(const float4*)&cur[3456 + p];
            slotT = (base + 64 + p) & RMASK;
            rvv = *(float4*)&ring[slotT];
        }
        __builtin_amdgcn_sched_barrier(0);   // pin all reads at phase top

        // (2) head finish -> w_{i+1} slice in registers
        {
            float v = clip1(rr + (((c0 + c1) + c2) + c3));
            float wn = hann_s * v;
            if (kg >= 2 && wlow) vb_w[s] = v;   // head v for next phase's kg<2
            if (wlow) wb_w[s] = wn;             // w_{i+1} for OLA
            wreg = wn;
        }

        // (3) FMA partials of conv_{i+1} -> nxt
        float a0 = 0, a1 = 0, a2 = 0, a3 = 0, a4 = 0, a5 = 0;
#pragma unroll
        for (int kk = 0; kk < 32; ++kk) {
            float sc = __int_as_float(__builtin_amdgcn_readlane(__float_as_int(wreg), 31 - kk));
            a0 = fmaf(sc, wir[kk + 0], a0);
            a1 = fmaf(sc, wir[kk + 1], a1);
            a2 = fmaf(sc, wir[kk + 2], a2);
            a3 = fmaf(sc, wir[kk + 3], a3);
            a4 = fmaf(sc, wir[kk + 4], a4);
            a5 = fmaf(sc, wir[kk + 5], a5);
        }
        float* pw = nxt + kg * 1152 + q;
        *(float2*)(pw + 0) = make_float2(a0, a1);
        *(float2*)(pw + 2) = make_float2(a2, a3);
        *(float2*)(pw + 4) = make_float2(a4, a5);

        // (4) OLA block i (wave 0) / x-commit + prefetch (wave 11) — off the
        // critical chain, placed after the FMA stream.
        if (wvid == 0) {
            float w0v = wb_r[lane];
            float w1v = wb_r[64 + lane];
            out[base + lane] = clip1(w0v + tl);
            tl = w1v;
        } else if (wvid == 11) {
            int pos = base + 1216 + lane;
            if (pos < SLEN) ring[pos & RMASK] = clip1(xv);
            int np = pos + HOPW;
            xv = (np < SLEN) ? x[np] : 0.f;
        }

        // (5) LATE: tail-apply RMW + write (reads from step 1 long since landed)
        if (tailw) {
            rvv.x = clip1(rvv.x + (((g0.x + g1.x) + g2.x) + g3.x));
            rvv.y = clip1(rvv.y + (((g0.y + g1.y) + g2.y) + g3.y));
            rvv.z = clip1(rvv.z + (((g0.z + g1.z) + g2.z) + g3.z));
            rvv.w = clip1(rvv.w + (((g0.w + g1.w) + g2.w) + g3.w));
            *(float4*)&ring[slotT] = rvv;
        }

        loop_barrier();
    };

    const float* P0 = &part[0][0][0];
    float* P1 = &part[1][0][0];
#pragma unroll 1
    for (int i = 0; i < NFB; i += 2) {   // NFB even -> parities compile-time
        body(i,     P0, (float*)P1, vbuf[1], vbuf[0], wb[0], wb[1]);
        body(i + 1, P1, (float*)P0, vbuf[0], vbuf[1], wb[1], wb[0]);
    }

    // ---- epilogue: blocks 1006/1007 + zero tail ----
    if (wvid == 0) {
        out[64384 + lane] = clip1(wb[0][lane] + tl);
        out[64448 + lane] = clip1(wb[0][64 + lane]);
    }
    for (int idx = 64512 + tid; idx < SLEN; idx += 768) out[idx] = 0.f;
}

extern "C" void kernel_launch(void* const* d_in, const int* in_sizes, int n_in,
                              void* d_out, int out_size, void* d_ws, size_t ws_size,
                              hipStream_t stream) {
    const float* x = (const float*)d_in[0];
    const float* ir = (const float*)d_in[1];
    float* out = (float*)d_out;
    (void)d_ws; (void)ws_size; (void)in_sizes; (void)n_in; (void)out_size;

    hipLaunchKernelGGL(howl_fused, dim3(1), dim3(768), 0, stream, x, ir, out);
}